// Round 1
// baseline (219.696 us; speedup 1.0000x reference)
//
#include <hip/hip_runtime.h>
#include <math.h>

// Each float4 holds two consecutive 2-d states: (x0,y0,x1,y1).
// out = (C*x + S*y, -S*x + C*y) where [C,S] is the exact composite of the
// 1000 float32-rounded rotation steps, computed in double on the host.
__global__ __launch_bounds__(256) void lin2d_rot_kernel(
    const float4* __restrict__ in, float4* __restrict__ out,
    int n4, float C, float S) {
    int i = blockIdx.x * blockDim.x + threadIdx.x;
    if (i < n4) {
        float4 v = in[i];
        float4 r;
        r.x =  C * v.x + S * v.y;
        r.y = -S * v.x + C * v.y;
        r.z =  C * v.z + S * v.w;
        r.w = -S * v.z + C * v.w;
        out[i] = r;
    }
}

extern "C" void kernel_launch(void* const* d_in, const int* in_sizes, int n_in,
                              void* d_out, int out_size, void* d_ws, size_t ws_size,
                              hipStream_t stream) {
    (void)d_ws; (void)ws_size; (void)n_in;

    // Reproduce the float32-rounded per-step constants, then compose exactly
    // in double: M = [[c,s],[-s,c]] acting on column (x0,x1) per step.
    // M^1000 = r^1000 * [[cos(1000*phi), sin(1000*phi)], [-sin, cos]].
    const double theta = M_PI / 100.0;
    const float cf = (float)cos(theta);
    const float sf = (float)sin(theta);
    const double r   = sqrt((double)cf * cf + (double)sf * sf);
    const double phi = atan2((double)sf, (double)cf);
    const double scale = pow(r, 1000.0);
    const double ang   = 1000.0 * phi;
    const float C = (float)(scale * cos(ang));
    const float S = (float)(scale * sin(ang));

    const float4* in  = (const float4*)d_in[0];
    float4*       out = (float4*)d_out;
    const int n_elems = in_sizes[0];      // 16777216 * 2 floats
    const int n4 = n_elems / 4;           // two states per float4

    const int block = 256;
    const int grid = (n4 + block - 1) / block;
    lin2d_rot_kernel<<<grid, block, 0, stream>>>(in, out, n4, C, S);
}